// Round 6
// baseline (65.045 us; speedup 1.0000x reference)
//
#include <hip/hip_runtime.h>

// LinearAccInterpolation: B x (NKP keyframes) x DIM=2.
// Per segment i (n = idx[i+1]-idx[i]):
//   da = (dy - n*v0 - n(n+1)/2*a0) / (n(n+1)(n+2)/6)
//   pos_k = y0 + k*v0 + k(k+1)/2*a0 + k(k+1)(k+2)/6*da   (k=1..n)
//   v0 += n*a0 + n(n+1)/2*da ;  a0 += n*da
// n<=1: emit y1; a0 = (y1-y0) - v0; v0 = y1-y0.
//
// index[] is shared by ALL batches -> segment lengths are launch-uniform.
// Fast path (all n==4, rows==4*NSEG, NSEG even): PT=NSEG/2... no: PT=5
// threads per batch, thread j owns segments {2j,2j+1} = rows 8j..8j+7 =
// exactly one 64B line at byte offset (b*5+j)*64. Each thread runs the
// full recurrence redundantly (~200 VALU) and emits its 8 rows into 4
// f4 registers (static indices only), then 4 nontemporal dwordx4 stores:
// a wave writes 4KB fully contiguous. No output LDS staging, no second
// barrier, no copy-out phase.
// Inputs are block-staged densely into LDS (6.6KB) as f4, then read
// back per-thread (13 distinct even banks per ds_read_b64 -> conflict-free).

typedef float f4 __attribute__((ext_vector_type(4)));

template <int NSEG>
__global__ __launch_bounds__(1024) void interp_fast(
    const int* __restrict__ index,
    const float2* __restrict__ value,      // B x NKP
    const float2* __restrict__ vinit,      // B x 1
    const float2* __restrict__ ainit,      // B x 1
    float2* __restrict__ out,              // B x rows
    int B, int rows, int PT)               // blockDim.x == 64*PT
{
    constexpr int NKP = NSEG + 1;
    __shared__ float2 sv[64 * NKP];
    __shared__ float2 svi[64];
    __shared__ float2 sai[64];

    int tid = threadIdx.x;
    int nthr = blockDim.x;
    int first_b = blockIdx.x * 64;
    int nb = B - first_b;
    if (nb > 64) nb = 64;

    // ---- dense copy-in (global -> LDS) ----
    if (nb == 64) {
        const f4* gv = (const f4*)(value + (long)first_b * NKP);
        f4* lv = (f4*)sv;
        constexpr int NV4 = 32 * NKP;                  // 352 for NKP=11
        for (int f = tid; f < NV4; f += nthr) lv[f] = gv[f];
        if (tid < 32) ((f4*)svi)[tid] = ((const f4*)(vinit + first_b))[tid];
        else if (tid < 64) ((f4*)sai)[tid - 32] = ((const f4*)(ainit + first_b))[tid - 32];
    } else {
        for (int f = tid; f < nb * NKP; f += nthr) sv[f] = value[(long)first_b * NKP + f];
        if (tid < nb) svi[tid] = vinit[first_b + tid];
        else if (tid >= 64 && tid < 64 + nb) sai[tid - 64] = ainit[first_b + tid - 64];
    }
    __syncthreads();

    int bl, j;
    if (PT == 5) { bl = tid / 5; j = tid - bl * 5; }   // literal div -> magic mul
    else         { bl = tid / PT; j = tid - bl * PT; }
    int b = first_b + bl;
    bool active = (bl < nb);

    // uniform segment lengths from the shared index[]
    int xi[NKP];
#pragma unroll
    for (int i = 0; i < NKP; ++i) xi[i] = index[i];    // uniform -> scalar loads

    bool fast = ((NSEG & 1) == 0) && (PT == NSEG / 2) && (rows == 4 * NSEG);
#pragma unroll
    for (int i = 0; i < NSEG; ++i) fast = fast && (xi[i + 1] - xi[i] == 4);

    if (!active) return;

    float2 y[NKP];
#pragma unroll
    for (int i = 0; i < NKP; ++i) y[i] = sv[bl * NKP + i];
    float2 v0 = svi[bl];
    float2 a0 = sai[bl];

    if (fast) {                                        // wave-uniform branch
        f4 b0, b1, b2, b3;
        int j2 = 2 * j;
#pragma unroll
        for (int i = 0; i < NSEG; ++i) {
            float2 y0 = y[i];
            float2 y1 = y[i + 1];
            float dyx = y1.x - y0.x;
            float dyy = y1.y - y0.y;
            // n=4: c1=10, c2=20
            float dax = (dyx - 4.0f * v0.x - 10.0f * a0.x) * 0.05f;
            float day = (dyy - 4.0f * v0.y - 10.0f * a0.y) * 0.05f;
            if (i == j2) {                             // rows 8j..8j+3
                b0.x = y0.x + v0.x + a0.x + dax;
                b0.y = y0.y + v0.y + a0.y + day;
                b0.z = y0.x + 2.0f * v0.x + 3.0f * a0.x + 4.0f * dax;
                b0.w = y0.y + 2.0f * v0.y + 3.0f * a0.y + 4.0f * day;
                b1.x = y0.x + 3.0f * v0.x + 6.0f * a0.x + 10.0f * dax;
                b1.y = y0.y + 3.0f * v0.y + 6.0f * a0.y + 10.0f * day;
                b1.z = y0.x + 4.0f * v0.x + 10.0f * a0.x + 20.0f * dax;
                b1.w = y0.y + 4.0f * v0.y + 10.0f * a0.y + 20.0f * day;
            } else if (i == j2 + 1) {                  // rows 8j+4..8j+7
                b2.x = y0.x + v0.x + a0.x + dax;
                b2.y = y0.y + v0.y + a0.y + day;
                b2.z = y0.x + 2.0f * v0.x + 3.0f * a0.x + 4.0f * dax;
                b2.w = y0.y + 2.0f * v0.y + 3.0f * a0.y + 4.0f * day;
                b3.x = y0.x + 3.0f * v0.x + 6.0f * a0.x + 10.0f * dax;
                b3.y = y0.y + 3.0f * v0.y + 6.0f * a0.y + 10.0f * day;
                b3.z = y0.x + 4.0f * v0.x + 10.0f * a0.x + 20.0f * dax;
                b3.w = y0.y + 4.0f * v0.y + 10.0f * a0.y + 20.0f * day;
            }
            v0.x += 4.0f * a0.x + 10.0f * dax;
            v0.y += 4.0f * a0.y + 10.0f * day;
            a0.x += 4.0f * dax;
            a0.y += 4.0f * day;
        }
        // one full 64B line per thread; wave = 4KB contiguous
        f4* o = (f4*)((char*)out + ((long)b * 5 + j) * 64);
        __builtin_nontemporal_store(b0, o + 0);
        __builtin_nontemporal_store(b1, o + 1);
        __builtin_nontemporal_store(b2, o + 2);
        __builtin_nontemporal_store(b3, o + 3);
    } else {
        // generality fallback (never taken for n==4 everywhere):
        // thread j owns rows [8j, 8j+8); predicated direct float2 stores.
        int g_lo = j * 8;
        int g_hi = g_lo + 8;
        if (g_hi > rows) g_hi = rows;
        float2* __restrict__ orow = out + (long)b * rows;
        int off = 0;
#pragma unroll
        for (int i = 0; i < NSEG; ++i) {
            float2 y0 = y[i];
            float2 y1 = y[i + 1];
            int n = xi[i + 1] - xi[i];
            float dyx = y1.x - y0.x;
            float dyy = y1.y - y0.y;
            if (n <= 1) {
                if (off >= g_lo && off < g_hi) orow[off] = y1;
                off += 1;
                a0.x = dyx - v0.x;
                a0.y = dyy - v0.y;
                v0.x = dyx;
                v0.y = dyy;
            } else {
                float fn = (float)n;
                float c1 = fn * (fn + 1.0f) * 0.5f;
                float c2 = fn * (fn + 1.0f) * (fn + 2.0f) / 6.0f;
                float rc2 = __builtin_amdgcn_rcpf(c2);
                float dax = (dyx - fn * v0.x - c1 * a0.x) * rc2;
                float day = (dyy - fn * v0.y - c1 * a0.y) * rc2;
                for (int k = 1; k <= n; ++k) {
                    int g = off + k - 1;
                    if (g >= g_lo && g < g_hi) {
                        float fk = (float)k;
                        float t2 = fk * (fk + 1.0f) * 0.5f;
                        float t3 = fk * (fk + 1.0f) * (fk + 2.0f) * (1.0f / 6.0f);
                        float2 p;
                        p.x = y0.x + fk * v0.x + t2 * a0.x + t3 * dax;
                        p.y = y0.y + fk * v0.y + t2 * a0.y + t3 * day;
                        orow[g] = p;
                    }
                }
                off += n;
                v0.x += fn * a0.x + c1 * dax;
                v0.y += fn * a0.y + c1 * day;
                a0.x += fn * dax;
                a0.y += fn * day;
            }
        }
    }
}

// Runtime-nseg fallback for unexpected nkp (or PT too large): one thread per
// (batch, row-chunk j), rolling y loads, predicated direct stores.
__global__ __launch_bounds__(256) void interp_gen(
    const int* __restrict__ index,
    const float2* __restrict__ value,
    const float2* __restrict__ vinit,
    const float2* __restrict__ ainit,
    float2* __restrict__ out,
    int B, int nkp, int rows, int PT)
{
    long t = (long)blockIdx.x * 256 + threadIdx.x;
    long total = (long)B * PT;
    if (t >= total) return;
    int b = (int)(t / PT);
    int j = (int)(t - (long)b * PT);
    int g_lo = j * 8;
    int g_hi = g_lo + 8;
    if (g_hi > rows) g_hi = rows;

    const float2* __restrict__ vrow = value + (long)b * nkp;
    float2* __restrict__ orow = out + (long)b * rows;
    float2 v0 = vinit[b];
    float2 a0 = ainit[b];
    float2 y0 = vrow[0];
    int x0 = index[0];
    int off = 0;
    for (int i = 0; i < nkp - 1; ++i) {
        float2 y1 = vrow[i + 1];
        int x1 = index[i + 1];
        int n = x1 - x0; x0 = x1;
        float dyx = y1.x - y0.x, dyy = y1.y - y0.y;
        if (n <= 1) {
            if (off >= g_lo && off < g_hi) orow[off] = y1;
            off += 1;
            a0.x = dyx - v0.x; a0.y = dyy - v0.y;
            v0.x = dyx; v0.y = dyy;
        } else {
            float fn = (float)n;
            float c1 = fn * (fn + 1.0f) * 0.5f;
            float c2 = fn * (fn + 1.0f) * (fn + 2.0f) / 6.0f;
            float dax = (dyx - fn * v0.x - c1 * a0.x) / c2;
            float day = (dyy - fn * v0.y - c1 * a0.y) / c2;
            for (int k = 1; k <= n; ++k) {
                int g = off + k - 1;
                if (g >= g_lo && g < g_hi) {
                    float fk = (float)k;
                    float t2 = fk * (fk + 1.0f) * 0.5f;
                    float t3 = fk * (fk + 1.0f) * (fk + 2.0f) * (1.0f / 6.0f);
                    float2 p;
                    p.x = y0.x + fk * v0.x + t2 * a0.x + t3 * dax;
                    p.y = y0.y + fk * v0.y + t2 * a0.y + t3 * day;
                    orow[g] = p;
                }
            }
            off += n;
            v0.x += fn * a0.x + c1 * dax;
            v0.y += fn * a0.y + c1 * day;
            a0.x += fn * dax;
            a0.y += fn * day;
        }
        y0 = y1;
    }
}

extern "C" void kernel_launch(void* const* d_in, const int* in_sizes, int n_in,
                              void* d_out, int out_size, void* d_ws, size_t ws_size,
                              hipStream_t stream) {
    const int*    index = (const int*)d_in[0];
    const float2* value = (const float2*)d_in[1];
    const float2* vinit = (const float2*)d_in[2];
    const float2* ainit = (const float2*)d_in[3];
    float2*       out   = (float2*)d_out;

    int nkp  = in_sizes[0];                 // 11
    int B    = in_sizes[1] / (nkp * 2);     // 262144
    int rows = out_size / (B * 2);          // 40
    int PT   = (rows + 7) / 8;              // threads per batch (5 for rows=40)

    if (nkp == 11 && PT >= 1 && PT <= 16) {
        dim3 grid((B + 63) / 64);
        interp_fast<10><<<grid, 64 * PT, 0, stream>>>(index, value, vinit, ainit, out, B, rows, PT);
    } else {
        long total = (long)B * PT;
        dim3 grid((unsigned)((total + 255) / 256));
        interp_gen<<<grid, 256, 0, stream>>>(index, value, vinit, ainit, out, B, nkp, rows, PT);
    }
}

// Round 7
// 41.841 us; speedup vs baseline: 1.5546x; 1.5546x over previous
//
#include <hip/hip_runtime.h>

// LinearAccInterpolation: B x (NKP keyframes) x DIM=2.
// Per segment i (n = idx[i+1]-idx[i]):
//   da = (dy - n*v0 - n(n+1)/2*a0) / (n(n+1)(n+2)/6)
//   pos_k = y0 + k*v0 + k(k+1)/2*a0 + k(k+1)(k+2)/6*da   (k=1..n)
//   v0 += n*a0 + n(n+1)/2*da ;  a0 += n*da
// n<=1: emit y1; a0 = (y1-y0) - v0; v0 = y1-y0.
//
// ROUND-6 LESSON: store coalescing is per WAVE INSTRUCTION. Thread-owns-
// 64B-line => each dwordx4 instruction strides 64B across lanes => 1.68x
// write amplification (WRITE_SIZE 141MB). Fix: ONE 16B chunk (2 rows) per
// thread, ONE nt store; lane l writes base+l*16 => 1KB contiguous per
// instruction, full lines, no output LDS staging at all.
//
// Fast path (index uniform n==4, rows==4*NSEG): PT=2*NSEG=20 threads per
// batch; thread m owns segment i=m>>1, half h=m&1 (rows k=1,2 or k=3,4).
// Each thread advances (v,a) through segments 0..i-1 with the n=4-reduced
// update  v' = 0.5dy - v - a ;  a' = 0.2dy - 0.8v - a   (da eliminated),
// then da = 0.05dy - 0.2v - 0.5a only at its own segment, evaluates its
// 2 rows branchlessly (k = 1+2h, 2+2h), packs f4, single nt store.
// Inputs block-staged in LDS (32 batches, 2.8KB); prefix-loop reads hit
// <=4 distinct LDS addresses per wave (broadcast, conflict-free).

typedef float f4 __attribute__((ext_vector_type(4)));

template <int NSEG>
__global__ __launch_bounds__(64 * NSEG) void interp_fast(
    const int* __restrict__ index,
    const float2* __restrict__ value,      // B x NKP
    const float2* __restrict__ vinit,      // B x 1
    const float2* __restrict__ ainit,      // B x 1
    float2* __restrict__ out,              // B x rows
    int B, int rows)
{
    constexpr int NKP = NSEG + 1;
    constexpr int PT  = 2 * NSEG;          // threads per batch (20)
    constexpr int BPB = 32;                // batches per block
    constexpr int NTHR = BPB * PT;         // 640

    __shared__ float2 sv[BPB * NKP];
    __shared__ float2 svi[BPB];
    __shared__ float2 sai[BPB];

    int tid = threadIdx.x;
    int first_b = blockIdx.x * BPB;
    int nb = B - first_b;
    if (nb > BPB) nb = BPB;

    // ---- dense copy-in (global -> LDS) ----
    if (nb == BPB) {
        const f4* gv = (const f4*)(value + (long)first_b * NKP);
        f4* lv = (f4*)sv;
        constexpr int NV4 = BPB * NKP / 2;             // 176 for NKP=11
        for (int f = tid; f < NV4; f += NTHR) lv[f] = gv[f];
        if (tid < BPB / 2) ((f4*)svi)[tid] = ((const f4*)(vinit + first_b))[tid];
        else if (tid < BPB) ((f4*)sai)[tid - BPB / 2] = ((const f4*)(ainit + first_b))[tid - BPB / 2];
    } else {
        for (int f = tid; f < nb * NKP; f += NTHR) sv[f] = value[(long)first_b * NKP + f];
        if (tid < nb) svi[tid] = vinit[first_b + tid];
        else if (tid >= BPB && tid < BPB + nb) sai[tid - BPB] = ainit[first_b + tid - BPB];
    }
    __syncthreads();

    int bl = tid / PT;                     // local batch
    int m  = tid - bl * PT;                // chunk-in-batch 0..PT-1
    if (bl >= nb) return;
    int b = first_b + bl;

    int xi[NKP];
#pragma unroll
    for (int i = 0; i < NKP; ++i) xi[i] = index[i];    // uniform -> scalar

    bool fast = (rows == 4 * NSEG);
#pragma unroll
    for (int i = 0; i < NSEG; ++i) fast = fast && (xi[i + 1] - xi[i] == 4);

    float2 v0 = svi[bl];
    float2 a0 = sai[bl];
    const float2* __restrict__ yrow = sv + bl * NKP;

    if (fast) {                                        // wave-uniform branch
        int i = m >> 1;                                // owned segment
        int h = m & 1;                                 // half: rows k=1,2 or 3,4

        float2 y0 = yrow[0];
        for (int s = 0; s < i; ++s) {                  // state-only prefix
            float2 y1 = yrow[s + 1];
            float dyx = y1.x - y0.x;
            float dyy = y1.y - y0.y;
            float vx = 0.5f * dyx - v0.x - a0.x;
            float vy = 0.5f * dyy - v0.y - a0.y;
            a0.x = 0.2f * dyx - 0.8f * v0.x - a0.x;
            a0.y = 0.2f * dyy - 0.8f * v0.y - a0.y;
            v0.x = vx; v0.y = vy;
            y0 = y1;
        }
        float2 y1 = yrow[i + 1];
        float dyx = y1.x - y0.x;
        float dyy = y1.y - y0.y;
        float dax = 0.05f * dyx - 0.2f * v0.x - 0.5f * a0.x;
        float day = 0.05f * dyy - 0.2f * v0.y - 0.5f * a0.y;

        float fk1 = (float)(1 + 2 * h);
        float fk2 = fk1 + 1.0f;
        float t2a = 0.5f * fk1 * (fk1 + 1.0f);
        float t3a = t2a * (fk1 + 2.0f) * (1.0f / 3.0f);
        float t2b = 0.5f * fk2 * (fk2 + 1.0f);
        float t3b = t2b * (fk2 + 2.0f) * (1.0f / 3.0f);

        f4 o;
        o.x = y0.x + fk1 * v0.x + t2a * a0.x + t3a * dax;
        o.y = y0.y + fk1 * v0.y + t2a * a0.y + t3a * day;
        o.z = y0.x + fk2 * v0.x + t2b * a0.x + t3b * dax;
        o.w = y0.y + fk2 * v0.y + t2b * a0.y + t3b * day;

        // chunk (b*PT + m) == first_b*PT + tid : 1KB contiguous per wave store
        __builtin_nontemporal_store(o, (f4*)out + (long)first_b * PT + tid);
    } else {
        // general fallback (not taken for uniform n==4): thread owns global
        // rows [2m, 2m+2); predicated direct float2 stores.
        int g_lo = 2 * m;
        int g_hi = g_lo + 2;
        if (g_hi > rows) g_hi = rows;
        float2* __restrict__ orow = out + (long)b * rows;
        float2 y0 = yrow[0];
        int off = 0;
#pragma unroll
        for (int i = 0; i < NSEG; ++i) {
            float2 y1 = yrow[i + 1];
            int n = xi[i + 1] - xi[i];
            float dyx = y1.x - y0.x;
            float dyy = y1.y - y0.y;
            if (n <= 1) {
                if (off >= g_lo && off < g_hi) orow[off] = y1;
                off += 1;
                a0.x = dyx - v0.x;
                a0.y = dyy - v0.y;
                v0.x = dyx;
                v0.y = dyy;
            } else {
                float fn = (float)n;
                float c1 = fn * (fn + 1.0f) * 0.5f;
                float c2 = fn * (fn + 1.0f) * (fn + 2.0f) / 6.0f;
                float rc2 = __builtin_amdgcn_rcpf(c2);
                float dax = (dyx - fn * v0.x - c1 * a0.x) * rc2;
                float day = (dyy - fn * v0.y - c1 * a0.y) * rc2;
                for (int k = 1; k <= n; ++k) {
                    int g = off + k - 1;
                    if (g >= g_lo && g < g_hi) {
                        float fk = (float)k;
                        float t2 = fk * (fk + 1.0f) * 0.5f;
                        float t3 = fk * (fk + 1.0f) * (fk + 2.0f) * (1.0f / 6.0f);
                        float2 p;
                        p.x = y0.x + fk * v0.x + t2 * a0.x + t3 * dax;
                        p.y = y0.y + fk * v0.y + t2 * a0.y + t3 * day;
                        orow[g] = p;
                    }
                }
                off += n;
                v0.x += fn * a0.x + c1 * dax;
                v0.y += fn * a0.y + c1 * day;
                a0.x += fn * dax;
                a0.y += fn * day;
            }
            y0 = y1;
        }
    }
}

// Runtime-nseg fallback for unexpected nkp/rows: one thread per
// (batch, 8-row chunk), rolling y loads, predicated direct stores.
__global__ __launch_bounds__(256) void interp_gen(
    const int* __restrict__ index,
    const float2* __restrict__ value,
    const float2* __restrict__ vinit,
    const float2* __restrict__ ainit,
    float2* __restrict__ out,
    int B, int nkp, int rows, int PT)
{
    long t = (long)blockIdx.x * 256 + threadIdx.x;
    long total = (long)B * PT;
    if (t >= total) return;
    int b = (int)(t / PT);
    int j = (int)(t - (long)b * PT);
    int g_lo = j * 8;
    int g_hi = g_lo + 8;
    if (g_hi > rows) g_hi = rows;

    const float2* __restrict__ vrow = value + (long)b * nkp;
    float2* __restrict__ orow = out + (long)b * rows;
    float2 v0 = vinit[b];
    float2 a0 = ainit[b];
    float2 y0 = vrow[0];
    int x0 = index[0];
    int off = 0;
    for (int i = 0; i < nkp - 1; ++i) {
        float2 y1 = vrow[i + 1];
        int x1 = index[i + 1];
        int n = x1 - x0; x0 = x1;
        float dyx = y1.x - y0.x, dyy = y1.y - y0.y;
        if (n <= 1) {
            if (off >= g_lo && off < g_hi) orow[off] = y1;
            off += 1;
            a0.x = dyx - v0.x; a0.y = dyy - v0.y;
            v0.x = dyx; v0.y = dyy;
        } else {
            float fn = (float)n;
            float c1 = fn * (fn + 1.0f) * 0.5f;
            float c2 = fn * (fn + 1.0f) * (fn + 2.0f) / 6.0f;
            float dax = (dyx - fn * v0.x - c1 * a0.x) / c2;
            float day = (dyy - fn * v0.y - c1 * a0.y) / c2;
            for (int k = 1; k <= n; ++k) {
                int g = off + k - 1;
                if (g >= g_lo && g < g_hi) {
                    float fk = (float)k;
                    float t2 = fk * (fk + 1.0f) * 0.5f;
                    float t3 = fk * (fk + 1.0f) * (fk + 2.0f) * (1.0f / 6.0f);
                    float2 p;
                    p.x = y0.x + fk * v0.x + t2 * a0.x + t3 * dax;
                    p.y = y0.y + fk * v0.y + t2 * a0.y + t3 * day;
                    orow[g] = p;
                }
            }
            off += n;
            v0.x += fn * a0.x + c1 * dax;
            v0.y += fn * a0.y + c1 * day;
            a0.x += fn * dax;
            a0.y += fn * day;
        }
        y0 = y1;
    }
}

extern "C" void kernel_launch(void* const* d_in, const int* in_sizes, int n_in,
                              void* d_out, int out_size, void* d_ws, size_t ws_size,
                              hipStream_t stream) {
    const int*    index = (const int*)d_in[0];
    const float2* value = (const float2*)d_in[1];
    const float2* vinit = (const float2*)d_in[2];
    const float2* ainit = (const float2*)d_in[3];
    float2*       out   = (float2*)d_out;

    int nkp  = in_sizes[0];                 // 11
    int B    = in_sizes[1] / (nkp * 2);     // 262144
    int rows = out_size / (B * 2);          // 40

    if (nkp == 11 && rows == 40) {
        // fast kernel: 32 batches/block, 20 threads/batch
        dim3 grid((B + 31) / 32);
        interp_fast<10><<<grid, 640, 0, stream>>>(index, value, vinit, ainit, out, B, rows);
    } else {
        int PT = (rows + 7) / 8;
        long total = (long)B * PT;
        dim3 grid((unsigned)((total + 255) / 256));
        interp_gen<<<grid, 256, 0, stream>>>(index, value, vinit, ainit, out, B, nkp, rows, PT);
    }
}

// Round 8
// 31.637 us; speedup vs baseline: 2.0559x; 1.3225x over previous
//
#include <hip/hip_runtime.h>

// LinearAccInterpolation: B x (NKP keyframes) x DIM=2.
// Per segment i (n = idx[i+1]-idx[i]):
//   da = (dy - n*v0 - n(n+1)/2*a0) / (n(n+1)(n+2)/6)
//   pos_k = y0 + k*v0 + k(k+1)/2*a0 + k(k+1)(k+2)/6*da   (k=1..n)
//   v0 += n*a0 + n(n+1)/2*da ;  a0 += n*da
// n<=1: emit y1; a0 = (y1-y0) - v0; v0 = y1-y0.
//
// ROUND-6 LESSON: store coalescing is per WAVE INSTRUCTION -> one 16B
// chunk per thread, one nt dwordx4 store, lane l at base+l*16 (1KB
// contiguous per wave store). WRITE_SIZE measured exactly ideal (81920KB).
// ROUND-7 LESSON: a per-lane-trip-count prefix loop with ds_read in the
// dependent chain is latency-bound (1.6TB/s, VALU 41%). Fix: two passes.
//   Pass1 (2 thr/batch, one per dim): n=4-reduced state recurrence
//     v' = 0.5dy - v - a ;  a' = 0.2dy - 0.8v - a   (da eliminated),
//     fully unrolled, states (v_i,a_i) -> LDS. Runs once per batch.
//   Pass2 (20 thr/batch): thread m (i=m>>1,h=m&1) reads y_i,y_{i+1},v_i,a_i
//     from LDS (4 reads, one wait), da = .05dy-.2v-.5a, evaluates rows
//     k=1+2h,2+2h with selected constant weights, single nt store.

typedef float f4 __attribute__((ext_vector_type(4)));

template <int NSEG>
__global__ __launch_bounds__(64 * NSEG) void interp_fast(
    const int* __restrict__ index,
    const float2* __restrict__ value,      // B x NKP
    const float2* __restrict__ vinit,      // B x 1
    const float2* __restrict__ ainit,      // B x 1
    float2* __restrict__ out,              // B x rows
    int B, int rows)
{
    constexpr int NKP = NSEG + 1;
    constexpr int PT  = 2 * NSEG;          // threads per batch (20)
    constexpr int BPB = 32;                // batches per block
    constexpr int NTHR = BPB * PT;         // 640

    __shared__ float2 sv[BPB * NKP];       // keyframe values
    __shared__ float2 svi[BPB];            // init speed
    __shared__ float2 sai[BPB];            // init acc
    __shared__ float2 st_v[BPB * NSEG];    // per-segment entry state v_i
    __shared__ float2 st_a[BPB * NSEG];    // per-segment entry state a_i

    int tid = threadIdx.x;
    int first_b = blockIdx.x * BPB;
    int nb = B - first_b;
    if (nb > BPB) nb = BPB;

    // ---- stage inputs (global -> LDS, dense f4) ----
    if (nb == BPB) {
        const f4* gv = (const f4*)(value + (long)first_b * NKP);
        f4* lv = (f4*)sv;
        constexpr int NV4 = BPB * NKP / 2;             // 176 for NKP=11
        for (int f = tid; f < NV4; f += NTHR) lv[f] = gv[f];
        if (tid < BPB / 2) ((f4*)svi)[tid] = ((const f4*)(vinit + first_b))[tid];
        else if (tid < BPB) ((f4*)sai)[tid - BPB / 2] = ((const f4*)(ainit + first_b))[tid - BPB / 2];
    } else {
        for (int f = tid; f < nb * NKP; f += NTHR) sv[f] = value[(long)first_b * NKP + f];
        if (tid < nb) svi[tid] = vinit[first_b + tid];
        else if (tid >= BPB && tid < BPB + nb) sai[tid - BPB] = ainit[first_b + tid - BPB];
    }

    // uniform segment lengths (same index[] for every batch & thread)
    int xi[NKP];
#pragma unroll
    for (int i = 0; i < NKP; ++i) xi[i] = index[i];    // uniform -> scalar

    bool fast = (rows == 4 * NSEG);
#pragma unroll
    for (int i = 0; i < NSEG; ++i) fast = fast && (xi[i + 1] - xi[i] == 4);

    __syncthreads();

    // ---- pass 1: per-batch state chain (fast path only) ----
    if (fast && tid < 2 * BPB) {
        int bl1 = tid >> 1;
        int d   = tid & 1;                 // dim (x/y are independent)
        if (bl1 < nb) {
            const float* yb = (const float*)(sv + bl1 * NKP) + d;   // stride-2 floats
            float v = ((const float*)(svi + bl1))[d];
            float a = ((const float*)(sai + bl1))[d];
            float* stv = (float*)(st_v + bl1 * NSEG) + d;
            float* sta = (float*)(st_a + bl1 * NSEG) + d;
            float yc = yb[0];
#pragma unroll
            for (int s = 0; s < NSEG; ++s) {
                stv[2 * s] = v;
                sta[2 * s] = a;
                float yn = yb[2 * (s + 1)];
                float dy = yn - yc;
                float vn = 0.5f * dy - v - a;
                a = 0.2f * dy - 0.8f * v - a;
                v = vn;
                yc = yn;
            }
        }
    }
    __syncthreads();

    int bl = tid / PT;                     // local batch
    int m  = tid - bl * PT;                // chunk-in-batch 0..PT-1
    if (bl >= nb) return;
    int b = first_b + bl;

    if (fast) {                                        // uniform branch
        int i = m >> 1;                                // owned segment
        int h = m & 1;                                 // rows k=1,2 or 3,4

        float2 y0 = sv[bl * NKP + i];
        float2 y1 = sv[bl * NKP + i + 1];
        float2 v  = st_v[bl * NSEG + i];
        float2 a  = st_a[bl * NSEG + i];

        float dax = 0.05f * (y1.x - y0.x) - 0.2f * v.x - 0.5f * a.x;
        float day = 0.05f * (y1.y - y0.y) - 0.2f * v.y - 0.5f * a.y;

        // k=1:(t2,t3)=(1,1) k=2:(3,4) k=3:(6,10) k=4:(10,20)
        float fk1 = h ? 3.0f : 1.0f;
        float fk2 = fk1 + 1.0f;
        float t2a = h ? 6.0f  : 1.0f;
        float t3a = h ? 10.0f : 1.0f;
        float t2b = h ? 10.0f : 3.0f;
        float t3b = h ? 20.0f : 4.0f;

        f4 o;
        o.x = y0.x + fk1 * v.x + t2a * a.x + t3a * dax;
        o.y = y0.y + fk1 * v.y + t2a * a.y + t3a * day;
        o.z = y0.x + fk2 * v.x + t2b * a.x + t3b * dax;
        o.w = y0.y + fk2 * v.y + t2b * a.y + t3b * day;

        // chunk (b*PT + m) == first_b*PT + tid : 1KB contiguous per wave store
        __builtin_nontemporal_store(o, (f4*)out + (long)first_b * PT + tid);
    } else {
        // general fallback (not taken for uniform n==4): thread owns global
        // rows [2m, 2m+2); predicated direct float2 stores.
        float2 v0 = svi[bl];
        float2 a0 = sai[bl];
        const float2* __restrict__ yrow = sv + bl * NKP;
        int g_lo = 2 * m;
        int g_hi = g_lo + 2;
        if (g_hi > rows) g_hi = rows;
        float2* __restrict__ orow = out + (long)b * rows;
        float2 y0 = yrow[0];
        int off = 0;
#pragma unroll
        for (int i = 0; i < NSEG; ++i) {
            float2 y1 = yrow[i + 1];
            int n = xi[i + 1] - xi[i];
            float dyx = y1.x - y0.x;
            float dyy = y1.y - y0.y;
            if (n <= 1) {
                if (off >= g_lo && off < g_hi) orow[off] = y1;
                off += 1;
                a0.x = dyx - v0.x;
                a0.y = dyy - v0.y;
                v0.x = dyx;
                v0.y = dyy;
            } else {
                float fn = (float)n;
                float c1 = fn * (fn + 1.0f) * 0.5f;
                float c2 = fn * (fn + 1.0f) * (fn + 2.0f) / 6.0f;
                float rc2 = __builtin_amdgcn_rcpf(c2);
                float dax = (dyx - fn * v0.x - c1 * a0.x) * rc2;
                float day = (dyy - fn * v0.y - c1 * a0.y) * rc2;
                for (int k = 1; k <= n; ++k) {
                    int g = off + k - 1;
                    if (g >= g_lo && g < g_hi) {
                        float fk = (float)k;
                        float t2 = fk * (fk + 1.0f) * 0.5f;
                        float t3 = fk * (fk + 1.0f) * (fk + 2.0f) * (1.0f / 6.0f);
                        float2 p;
                        p.x = y0.x + fk * v0.x + t2 * a0.x + t3 * dax;
                        p.y = y0.y + fk * v0.y + t2 * a0.y + t3 * day;
                        orow[g] = p;
                    }
                }
                off += n;
                v0.x += fn * a0.x + c1 * dax;
                v0.y += fn * a0.y + c1 * day;
                a0.x += fn * dax;
                a0.y += fn * day;
            }
            y0 = y1;
        }
    }
}

// Runtime-nseg fallback for unexpected nkp/rows: one thread per
// (batch, 8-row chunk), rolling y loads, predicated direct stores.
__global__ __launch_bounds__(256) void interp_gen(
    const int* __restrict__ index,
    const float2* __restrict__ value,
    const float2* __restrict__ vinit,
    const float2* __restrict__ ainit,
    float2* __restrict__ out,
    int B, int nkp, int rows, int PT)
{
    long t = (long)blockIdx.x * 256 + threadIdx.x;
    long total = (long)B * PT;
    if (t >= total) return;
    int b = (int)(t / PT);
    int j = (int)(t - (long)b * PT);
    int g_lo = j * 8;
    int g_hi = g_lo + 8;
    if (g_hi > rows) g_hi = rows;

    const float2* __restrict__ vrow = value + (long)b * nkp;
    float2* __restrict__ orow = out + (long)b * rows;
    float2 v0 = vinit[b];
    float2 a0 = ainit[b];
    float2 y0 = vrow[0];
    int x0 = index[0];
    int off = 0;
    for (int i = 0; i < nkp - 1; ++i) {
        float2 y1 = vrow[i + 1];
        int x1 = index[i + 1];
        int n = x1 - x0; x0 = x1;
        float dyx = y1.x - y0.x, dyy = y1.y - y0.y;
        if (n <= 1) {
            if (off >= g_lo && off < g_hi) orow[off] = y1;
            off += 1;
            a0.x = dyx - v0.x; a0.y = dyy - v0.y;
            v0.x = dyx; v0.y = dyy;
        } else {
            float fn = (float)n;
            float c1 = fn * (fn + 1.0f) * 0.5f;
            float c2 = fn * (fn + 1.0f) * (fn + 2.0f) / 6.0f;
            float dax = (dyx - fn * v0.x - c1 * a0.x) / c2;
            float day = (dyy - fn * v0.y - c1 * a0.y) / c2;
            for (int k = 1; k <= n; ++k) {
                int g = off + k - 1;
                if (g >= g_lo && g < g_hi) {
                    float fk = (float)k;
                    float t2 = fk * (fk + 1.0f) * 0.5f;
                    float t3 = fk * (fk + 1.0f) * (fk + 2.0f) * (1.0f / 6.0f);
                    float2 p;
                    p.x = y0.x + fk * v0.x + t2 * a0.x + t3 * dax;
                    p.y = y0.y + fk * v0.y + t2 * a0.y + t3 * day;
                    orow[g] = p;
                }
            }
            off += n;
            v0.x += fn * a0.x + c1 * dax;
            v0.y += fn * a0.y + c1 * day;
            a0.x += fn * dax;
            a0.y += fn * day;
        }
        y0 = y1;
    }
}

extern "C" void kernel_launch(void* const* d_in, const int* in_sizes, int n_in,
                              void* d_out, int out_size, void* d_ws, size_t ws_size,
                              hipStream_t stream) {
    const int*    index = (const int*)d_in[0];
    const float2* value = (const float2*)d_in[1];
    const float2* vinit = (const float2*)d_in[2];
    const float2* ainit = (const float2*)d_in[3];
    float2*       out   = (float2*)d_out;

    int nkp  = in_sizes[0];                 // 11
    int B    = in_sizes[1] / (nkp * 2);     // 262144
    int rows = out_size / (B * 2);          // 40

    if (nkp == 11 && rows == 40) {
        // fast kernel: 32 batches/block, 20 threads/batch
        dim3 grid((B + 31) / 32);
        interp_fast<10><<<grid, 640, 0, stream>>>(index, value, vinit, ainit, out, B, rows);
    } else {
        int PT = (rows + 7) / 8;
        long total = (long)B * PT;
        dim3 grid((unsigned)((total + 255) / 256));
        interp_gen<<<grid, 256, 0, stream>>>(index, value, vinit, ainit, out, B, nkp, rows, PT);
    }
}

// Round 10
// 30.219 us; speedup vs baseline: 2.1524x; 1.0469x over previous
//
#include <hip/hip_runtime.h>

// LinearAccInterpolation: B x (NKP keyframes) x DIM=2.
// Per segment i (n = idx[i+1]-idx[i]):
//   da = (dy - n*v0 - n(n+1)/2*a0) / (n(n+1)(n+2)/6)
//   pos_k = y0 + k*v0 + k(k+1)/2*a0 + k(k+1)(k+2)/6*da   (k=1..n)
//   v0 += n*a0 + n(n+1)/2*da ;  a0 += n*da
// n<=1: emit y1; a0 = (y1-y0) - v0; v0 = y1-y0.
//
// LESSONS (measured):
//  R6: store coalescing is per WAVE INSTRUCTION => one 16B chunk per lane.
//  R7: LDS in a per-lane-trip dependent chain = latency-bound.
//  R8: tiny per-thread work + serialized phases = latency-bound.
//  R9: f4-count bug in staging (vinit/ainit are 32 f4 each, not 16) -> FIXED.
// Structure = R5 (best measured) + multi-tile blocks with async-STAGE split:
//  each block runs TPB=4 tiles; tile t+1's global loads are ISSUED into
//  registers before tile t's compute and WRITTEN to LDS after it, hiding
//  HBM latency under compute+copyout. 2 barriers/tile (was 3).

typedef float f4 __attribute__((ext_vector_type(4)));

template <int NSEG, int TPB>
__global__ __launch_bounds__(256) void interp_kernel(
    const int* __restrict__ index,
    const float2* __restrict__ value,      // B x NKP
    const float2* __restrict__ vinit,      // B x 1
    const float2* __restrict__ ainit,      // B x 1
    float2* __restrict__ out,              // B x rows
    int B, int rows, int pad2, int ntiles) // pad2 = padded row stride (f2)
{
    constexpr int NKP = NSEG + 1;
    constexpr int NV4 = 64 * NKP / 2;      // value-slab f4s per tile (352)
    constexpr int NI4 = 32;                // 64 float2 = 32 f4 per init array
    constexpr int NT4 = NV4 + 2 * NI4;     // 416 total staged f4s per tile

    extern __shared__ char smem[];
    float2* outt = (float2*)smem;                          // [64*pad2] out tile
    f4*     s_in = (f4*)(smem + (size_t)64 * pad2 * 8);    // [NT4] input slab
    float2* inv  = (float2*)s_in;                          // [64*NKP]
    float2* ivi  = (float2*)(s_in + NV4);                  // [64]
    float2* iai  = (float2*)(s_in + NV4 + NI4);            // [64]

    int tid = threadIdx.x;
    int bl  = tid >> 2;                    // local batch 0..63
    int r   = tid & 3;                     // lane-in-group

    int xi[NKP];
#pragma unroll
    for (int i = 0; i < NKP; ++i) xi[i] = index[i];        // uniform -> scalar

    int tile0 = blockIdx.x * TPB;
    if (tile0 >= ntiles) return;

    auto ld_stage = [&](int f, long fb) -> f4 {
        if (f < NV4) return ((const f4*)(value + fb * NKP))[f];
        else if (f < NV4 + NI4) return ((const f4*)(vinit + fb))[f - NV4];
        else return ((const f4*)(ainit + fb))[f - NV4 - NI4];
    };

    // ---- prologue: stage tile0 ----
    {
        long fb = (long)tile0 * 64;
        f4 r0 = ld_stage(tid, fb);
        f4 r1;
        if (tid < NT4 - 256) r1 = ld_stage(tid + 256, fb);
        s_in[tid] = r0;
        if (tid < NT4 - 256) s_in[tid + 256] = r1;
    }
    __syncthreads();

    for (int t = 0; t < TPB; ++t) {
        int tile = tile0 + t;
        if (tile >= ntiles) break;
        long first_b = (long)tile * 64;

        // ---- B1: LDS_in -> registers ----
        float2 y[NKP];
#pragma unroll
        for (int i = 0; i < NKP; ++i) y[i] = inv[bl * NKP + i];
        float2 v0 = ivi[bl];
        float2 a0 = iai[bl];
        __syncthreads();                   // all reads of LDS_in done

        // ---- issue-early: next tile's global loads into registers ----
        bool more = (t + 1 < TPB) && (tile + 1 < ntiles);
        f4 r0, r1;
        if (more) {
            long fb = first_b + 64;
            r0 = ld_stage(tid, fb);
            if (tid < NT4 - 256) r1 = ld_stage(tid + 256, fb);
        }

        // ---- B2: recurrence -> padded LDS out tile ----
        {
            float2* __restrict__ lrow = outt + bl * pad2;
            int off = 0;
#pragma unroll
            for (int i = 0; i < NSEG; ++i) {
                float2 y0 = y[i];
                float2 y1 = y[i + 1];
                int n = xi[i + 1] - xi[i];
                float dyx = y1.x - y0.x;
                float dyy = y1.y - y0.y;

                if (n <= 1) {
                    if (r == 0) lrow[off] = y1;
                    off += 1;
                    a0.x = dyx - v0.x;
                    a0.y = dyy - v0.y;
                    v0.x = dyx;
                    v0.y = dyy;
                } else {
                    float fn = (float)n;
                    float c1 = fn * (fn + 1.0f) * 0.5f;               // n(n+1)/2
                    float c2 = fn * (fn + 1.0f) * (fn + 2.0f) / 6.0f; // n(n+1)(n+2)/6
                    float rc2 = __builtin_amdgcn_rcpf(c2);            // ~2^-22 rel err
                    float dax = (dyx - fn * v0.x - c1 * a0.x) * rc2;
                    float day = (dyy - fn * v0.y - c1 * a0.y) * rc2;

                    for (int k = r + 1; k <= n; k += 4) {
                        float fk = (float)k;
                        float t2 = fk * (fk + 1.0f) * 0.5f;
                        float t3 = fk * (fk + 1.0f) * (fk + 2.0f) * (1.0f / 6.0f);
                        float2 p;
                        p.x = y0.x + fk * v0.x + t2 * a0.x + t3 * dax;
                        p.y = y0.y + fk * v0.y + t2 * a0.y + t3 * day;
                        lrow[off + k - 1] = p;
                    }
                    off += n;

                    v0.x += fn * a0.x + c1 * dax;
                    v0.y += fn * a0.y + c1 * day;
                    a0.x += fn * dax;
                    a0.y += fn * day;
                }
            }
        }

        // ---- write-late: staged regs -> LDS_in (vmcnt wait lands here) ----
        if (more) {
            s_in[tid] = r0;
            if (tid < NT4 - 256) s_in[tid + 256] = r1;
        }
        __syncthreads();                   // out tile ready; LDS_in ready

        // ---- C: coalesced nontemporal copy-out ----
        {
            int rowf4 = rows >> 1;                  // 20
            int padf4 = pad2 >> 1;                  // 21
            const f4* __restrict__ l4 = (const f4*)outt;
            f4* __restrict__ o4 = (f4*)(out + first_b * rows);
            int total4 = 64 * rowf4;
            int bb = tid / rowf4;
            int j  = tid - bb * rowf4;
            int stepb = 256 / rowf4;
            int stepj = 256 - stepb * rowf4;
            for (int f = tid; f < total4; f += 256) {
                __builtin_nontemporal_store(l4[bb * padf4 + j], &o4[f]);
                j += stepj; bb += stepb;
                if (j >= rowf4) { j -= rowf4; ++bb; }
            }
        }
        // copy-out's outt reads are separated from the next tile's outt
        // writes by the next iteration's post-B1 barrier.
    }
}

// Generic fallback (unexpected nkp / ragged B / odd rows).
__global__ __launch_bounds__(256) void interp_kernel_gen(
    const int* __restrict__ index,
    const float2* __restrict__ value,
    const float2* __restrict__ vinit,
    const float2* __restrict__ ainit,
    float2* __restrict__ out,
    int B, int nkp, int rows, int pad2)
{
    extern __shared__ char smem[];
    float2* lds = (float2*)smem;
    int tid = threadIdx.x;
    int gid = blockIdx.x * 256 + tid;
    int b  = gid >> 2;
    int r  = gid & 3;
    int bl = tid >> 2;

    if (b < B) {
        const float2* __restrict__ vrow = value + (long)b * nkp;
        float2* __restrict__ lrow = lds + bl * pad2;
        float2 v0 = vinit[b];
        float2 a0 = ainit[b];
        float2 y0 = vrow[0];
        int x0 = index[0];
        int off = 0;
        for (int i = 0; i < nkp - 1; ++i) {
            float2 y1 = vrow[i + 1];
            int x1 = index[i + 1];
            int n = x1 - x0; x0 = x1;
            float dyx = y1.x - y0.x, dyy = y1.y - y0.y;
            if (n <= 1) {
                if (r == 0) lrow[off] = y1;
                off += 1;
                a0.x = dyx - v0.x; a0.y = dyy - v0.y;
                v0.x = dyx; v0.y = dyy;
            } else {
                float fn = (float)n;
                float c1 = fn * (fn + 1.0f) * 0.5f;
                float c2 = fn * (fn + 1.0f) * (fn + 2.0f) / 6.0f;
                float dax = (dyx - fn * v0.x - c1 * a0.x) / c2;
                float day = (dyy - fn * v0.y - c1 * a0.y) / c2;
                for (int k = r + 1; k <= n; k += 4) {
                    float fk = (float)k;
                    float t2 = fk * (fk + 1.0f) * 0.5f;
                    float t3 = fk * (fk + 1.0f) * (fk + 2.0f) * (1.0f / 6.0f);
                    float2 p;
                    p.x = y0.x + fk * v0.x + t2 * a0.x + t3 * dax;
                    p.y = y0.y + fk * v0.y + t2 * a0.y + t3 * day;
                    lrow[off + k - 1] = p;
                }
                off += n;
                v0.x += fn * a0.x + c1 * dax;
                v0.y += fn * a0.y + c1 * day;
                a0.x += fn * dax;
                a0.y += fn * day;
            }
            y0 = y1;
        }
    }

    __syncthreads();

    int first_b = blockIdx.x * 64;
    int nb = B - first_b;
    if (nb > 64) nb = 64;
    if (nb <= 0) return;
    int total2 = nb * rows;
    float2* __restrict__ o2 = out + (long)first_b * rows;
    for (int f = tid; f < total2; f += 256) {
        int bb = f / rows;
        int j  = f - bb * rows;
        o2[f] = lds[bb * pad2 + j];
    }
}

extern "C" void kernel_launch(void* const* d_in, const int* in_sizes, int n_in,
                              void* d_out, int out_size, void* d_ws, size_t ws_size,
                              hipStream_t stream) {
    const int*    index = (const int*)d_in[0];
    const float2* value = (const float2*)d_in[1];
    const float2* vinit = (const float2*)d_in[2];
    const float2* ainit = (const float2*)d_in[3];
    float2*       out   = (float2*)d_out;

    int nkp  = in_sizes[0];                 // 11
    int B    = in_sizes[1] / (nkp * 2);     // 262144
    int rows = out_size / (B * 2);          // 40

    int pad2 = rows + 2;                    // f4-aligned rows, breaks bank stride

    if (nkp == 11 && (B % 64) == 0 && (rows % 2) == 0 && rows >= 2) {
        constexpr int TPB = 4;
        int ntiles = B / 64;                                   // 4096
        constexpr int NV4 = 64 * 11 / 2;
        size_t smem = (size_t)64 * pad2 * 8 + (size_t)(NV4 + 64) * 16; // 28160
        dim3 grid((ntiles + TPB - 1) / TPB);                   // 1024
        interp_kernel<10, TPB><<<grid, 256, smem, stream>>>(
            index, value, vinit, ainit, out, B, rows, pad2, ntiles);
    } else {
        size_t smem = (size_t)64 * pad2 * sizeof(float2);
        dim3 grid((B + 63) / 64);
        interp_kernel_gen<<<grid, 256, smem, stream>>>(
            index, value, vinit, ainit, out, B, nkp, rows, pad2);
    }
}

// Round 11
// 27.176 us; speedup vs baseline: 2.3935x; 1.1120x over previous
//
#include <hip/hip_runtime.h>

// LinearAccInterpolation: B x (NKP keyframes) x DIM=2.
// Per segment i (n = idx[i+1]-idx[i]):
//   da = (dy - n*v0 - n(n+1)/2*a0) / (n(n+1)(n+2)/6)
//   pos_k = y0 + k*v0 + k(k+1)/2*a0 + k(k+1)(k+2)/6*da   (k=1..n)
//   v0 += n*a0 + n(n+1)/2*da ;  a0 += n*da
// n<=1: emit y1; a0 = (y1-y0) - v0; v0 = y1-y0.
//
// LESSONS (measured):
//  R6: store coalescing is per WAVE INSTRUCTION => lane l must write
//      base + l*16; thread-owns-64B-line = 1.68x write amplification.
//  R7: LDS in a per-lane-trip dependent chain = latency-bound.
//  R8/R10: trading block-count for in-block pipelining (2-pass, TPB=4)
//      regresses — cross-block TLP is the latency hider here (4096 blocks).
//  R5 = best measured (23.9us): one 64-batch tile per 256-thread block;
//      dense f4 input staging -> regs -> recurrence -> padded LDS out tile
//      -> coalesced f4 copy-out.
// R11 = R5 with ONE change: plain (L2-buffered) stores instead of
//      nontemporal. The 6.9TB/s fill uses plain stores; nt bypasses L2 and
//      may expose raw HBM write latency. Single-variable A/B.

typedef float f4 __attribute__((ext_vector_type(4)));

template <int NSEG>
__global__ __launch_bounds__(256) void interp_kernel(
    const int* __restrict__ index,
    const float2* __restrict__ value,      // B x NKP
    const float2* __restrict__ vinit,      // B x 1
    const float2* __restrict__ ainit,      // B x 1
    float2* __restrict__ out,              // B x rows
    int B, int rows, int pad2)             // pad2 = padded row stride (float2)
{
    constexpr int NKP = NSEG + 1;
    extern __shared__ char smem[];
    // Phase A/B1 layout:
    float2* inv = (float2*)smem;                       // [64*NKP] value slab
    float2* ivi = (float2*)(smem + 64 * NKP * 8);      // [64] init_speed
    float2* iai = (float2*)(smem + 64 * NKP * 8 + 512);// [64] init_acc
    // Phase B2/C layout (aliased, reused after B1):
    float2* outt = (float2*)smem;                      // [64][pad2]

    int tid = threadIdx.x;
    int first_b = blockIdx.x * 64;
    int nb = B - first_b;
    if (nb > 64) nb = 64;
    bool full = (nb == 64);

    // ---- Phase A: copy-in ----
    if (full) {
        const f4* gv4 = (const f4*)(value + (long)first_b * NKP);
        f4* l4 = (f4*)inv;
        constexpr int NV4 = 64 * NKP / 2;              // 352 for NKP=11
        for (int f = tid; f < NV4; f += 256) l4[f] = gv4[f];
        if (tid < 32) {
            ((f4*)ivi)[tid] = ((const f4*)(vinit + first_b))[tid];
        } else if (tid < 64) {
            ((f4*)iai)[tid - 32] = ((const f4*)(ainit + first_b))[tid - 32];
        }
    } else {
        for (int f = tid; f < nb * NKP; f += 256) inv[f] = value[(long)first_b * NKP + f];
        if (tid < nb) ivi[tid] = vinit[first_b + tid];
        else if (tid < 2 * nb) iai[tid - nb] = ainit[first_b + tid - nb];
    }
    __syncthreads();

    // ---- Phase B1: LDS -> registers ----
    int bl = tid >> 2;                     // local batch 0..63
    int r  = tid & 3;                      // lane-in-group
    bool active = (bl < nb);

    float2 y[NKP];
    float2 v0, a0;
    int xi[NKP];
#pragma unroll
    for (int i = 0; i < NKP; ++i) xi[i] = index[i];    // uniform -> s_load
    if (active) {
#pragma unroll
        for (int i = 0; i < NKP; ++i) y[i] = inv[bl * NKP + i];
        v0 = ivi[bl];
        a0 = iai[bl];
    } else {
        v0 = a0 = make_float2(0.f, 0.f);
#pragma unroll
        for (int i = 0; i < NKP; ++i) y[i] = make_float2(0.f, 0.f);
    }
    __syncthreads();   // everyone done reading; LDS now reusable as out tile

    // ---- Phase B2: recurrence -> padded LDS tile ----
    if (active) {
        float2* __restrict__ lrow = outt + bl * pad2;
        int off = 0;
#pragma unroll
        for (int i = 0; i < NSEG; ++i) {
            float2 y0 = y[i];
            float2 y1 = y[i + 1];
            int n = xi[i + 1] - xi[i];
            float dyx = y1.x - y0.x;
            float dyy = y1.y - y0.y;

            if (n <= 1) {
                if (r == 0) lrow[off] = y1;
                off += 1;
                a0.x = dyx - v0.x;
                a0.y = dyy - v0.y;
                v0.x = dyx;
                v0.y = dyy;
            } else {
                float fn = (float)n;
                float c1 = fn * (fn + 1.0f) * 0.5f;               // n(n+1)/2
                float c2 = fn * (fn + 1.0f) * (fn + 2.0f) / 6.0f; // n(n+1)(n+2)/6
                float rc2 = __builtin_amdgcn_rcpf(c2);            // ~2^-22 rel err
                float dax = (dyx - fn * v0.x - c1 * a0.x) * rc2;
                float day = (dyy - fn * v0.y - c1 * a0.y) * rc2;

                for (int k = r + 1; k <= n; k += 4) {
                    float fk = (float)k;
                    float t2 = fk * (fk + 1.0f) * 0.5f;
                    float t3 = fk * (fk + 1.0f) * (fk + 2.0f) * (1.0f / 6.0f);
                    float2 p;
                    p.x = y0.x + fk * v0.x + t2 * a0.x + t3 * dax;
                    p.y = y0.y + fk * v0.y + t2 * a0.y + t3 * day;
                    lrow[off + k - 1] = p;
                }
                off += n;

                v0.x += fn * a0.x + c1 * dax;
                v0.y += fn * a0.y + c1 * day;
                a0.x += fn * dax;
                a0.y += fn * day;
            }
        }
    }
    __syncthreads();

    // ---- Phase C: coalesced copy-out (plain stores; A/B vs R5's nt) ----
    if (full && (rows & 1) == 0) {
        int rowf4 = rows >> 1;                  // 20
        int padf4 = pad2 >> 1;                  // 21
        const f4* __restrict__ l4 = (const f4*)outt;
        f4* __restrict__ o4 = (f4*)(out + (long)first_b * rows);
        int total4 = 64 * rowf4;
        int bb = tid / rowf4;
        int j  = tid - bb * rowf4;
        int stepb = 256 / rowf4;
        int stepj = 256 - stepb * rowf4;
        for (int f = tid; f < total4; f += 256) {
            o4[f] = l4[bb * padf4 + j];
            j += stepj; bb += stepb;
            if (j >= rowf4) { j -= rowf4; ++bb; }
        }
    } else if (nb > 0) {                        // generic tail
        int total2 = nb * rows;
        float2* __restrict__ o2 = out + (long)first_b * rows;
        for (int f = tid; f < total2; f += 256) {
            int bb = f / rows;
            int j  = f - bb * rows;
            o2[f] = outt[bb * pad2 + j];
        }
    }
}

// Runtime-NSEG fallback for unexpected nkp.
__global__ __launch_bounds__(256) void interp_kernel_gen(
    const int* __restrict__ index,
    const float2* __restrict__ value,
    const float2* __restrict__ vinit,
    const float2* __restrict__ ainit,
    float2* __restrict__ out,
    int B, int nkp, int rows, int pad2)
{
    extern __shared__ char smem[];
    float2* lds = (float2*)smem;
    int tid = threadIdx.x;
    int gid = blockIdx.x * 256 + tid;
    int b  = gid >> 2;
    int r  = gid & 3;
    int bl = tid >> 2;

    if (b < B) {
        const float2* __restrict__ vrow = value + (long)b * nkp;
        float2* __restrict__ lrow = lds + bl * pad2;
        float2 v0 = vinit[b];
        float2 a0 = ainit[b];
        float2 y0 = vrow[0];
        int x0 = index[0];
        int off = 0;
        for (int i = 0; i < nkp - 1; ++i) {
            float2 y1 = vrow[i + 1];
            int x1 = index[i + 1];
            int n = x1 - x0; x0 = x1;
            float dyx = y1.x - y0.x, dyy = y1.y - y0.y;
            if (n <= 1) {
                if (r == 0) lrow[off] = y1;
                off += 1;
                a0.x = dyx - v0.x; a0.y = dyy - v0.y;
                v0.x = dyx; v0.y = dyy;
            } else {
                float fn = (float)n;
                float c1 = fn * (fn + 1.0f) * 0.5f;
                float c2 = fn * (fn + 1.0f) * (fn + 2.0f) / 6.0f;
                float dax = (dyx - fn * v0.x - c1 * a0.x) / c2;
                float day = (dyy - fn * v0.y - c1 * a0.y) / c2;
                for (int k = r + 1; k <= n; k += 4) {
                    float fk = (float)k;
                    float t2 = fk * (fk + 1.0f) * 0.5f;
                    float t3 = fk * (fk + 1.0f) * (fk + 2.0f) * (1.0f / 6.0f);
                    float2 p;
                    p.x = y0.x + fk * v0.x + t2 * a0.x + t3 * dax;
                    p.y = y0.y + fk * v0.y + t2 * a0.y + t3 * day;
                    lrow[off + k - 1] = p;
                }
                off += n;
                v0.x += fn * a0.x + c1 * dax;
                v0.y += fn * a0.y + c1 * day;
                a0.x += fn * dax;
                a0.y += fn * day;
            }
            y0 = y1;
        }
    }

    __syncthreads();

    int first_b = blockIdx.x * 64;
    int nb = B - first_b;
    if (nb > 64) nb = 64;
    if (nb <= 0) return;
    int total2 = nb * rows;
    float2* __restrict__ o2 = out + (long)first_b * rows;
    for (int f = tid; f < total2; f += 256) {
        int bb = f / rows;
        int j  = f - bb * rows;
        o2[f] = lds[bb * pad2 + j];
    }
}

extern "C" void kernel_launch(void* const* d_in, const int* in_sizes, int n_in,
                              void* d_out, int out_size, void* d_ws, size_t ws_size,
                              hipStream_t stream) {
    const int*    index = (const int*)d_in[0];
    const float2* value = (const float2*)d_in[1];
    const float2* vinit = (const float2*)d_in[2];
    const float2* ainit = (const float2*)d_in[3];
    float2*       out   = (float2*)d_out;

    int nkp  = in_sizes[0];                 // 11
    int B    = in_sizes[1] / (nkp * 2);     // 262144
    int rows = out_size / (B * 2);          // 40

    int pad2 = rows + 2;                    // f4-aligned rows, breaks bank stride
    size_t smem_out = (size_t)64 * pad2 * sizeof(float2);       // 21504 for rows=40
    size_t smem_in  = (size_t)64 * nkp * sizeof(float2) + 1024; // 6656 for nkp=11
    size_t smem = smem_out > smem_in ? smem_out : smem_in;

    dim3 grid((B + 63) / 64);

    if (nkp == 11) {
        interp_kernel<10><<<grid, 256, smem, stream>>>(index, value, vinit, ainit, out, B, rows, pad2);
    } else {
        interp_kernel_gen<<<grid, 256, smem, stream>>>(index, value, vinit, ainit, out, B, nkp, rows, pad2);
    }
}